// Round 8
// baseline (395.726 us; speedup 1.0000x reference)
//
#include <hip/hip_runtime.h>
#include <float.h>

#define EPSV 1e-5f
#define DGRID 21
#define DPROD (21 * 21 * 21)

typedef __attribute__((ext_vector_type(8))) short bf16x8;
typedef __attribute__((ext_vector_type(4))) float f32x4;

// fp32 -> bf16 (RNE), bit pattern in short
__device__ __forceinline__ short f2bf(float x) {
    unsigned u = __float_as_uint(x);
    unsigned r = (u + 0x7FFFu + ((u >> 16) & 1u)) >> 16;
    return (short)r;
}

// ---------- helpers ----------
__device__ __forceinline__ int batch_of(int i, const int* __restrict__ offset, int B) {
    int b = 0;
    while (b < B - 1 && i >= offset[b]) ++b;
    return b;
}

// ---------- init: startEnc only (must complete before k_start's atomicMin) ----------
__global__ void k_init(int* startEnc, int B) {
    int tid = threadIdx.x;
    if (tid < B * 3) startEnc[tid] = 0x7FFFFFFF;              // +inf for non-neg floats
}

// ---------- per-batch coord min (segment_min) + counts zeroing ----------
__global__ void k_start(const float* __restrict__ coord, const int* __restrict__ offset,
                        int* startEnc, int* counts, int KSM, int N, int B) {
    int gtid = blockIdx.x * blockDim.x + threadIdx.x;
    for (int k = gtid; k < KSM; k += gridDim.x * blockDim.x) counts[k] = 0;

    __shared__ int smin[24];
    int t = threadIdx.x;
    if (t < B * 3) smin[t] = 0x7FFFFFFF;
    __syncthreads();
    int base = gtid * 4;
    int curb = -1;
    int m0 = 0x7FFFFFFF, m1 = 0x7FFFFFFF, m2 = 0x7FFFFFFF;
    for (int r = 0; r < 4; ++r) {
        int i = base + r;
        if (i >= N) break;
        int b = batch_of(i, offset, B);
        if (b != curb) {
            if (curb >= 0) {
                atomicMin(&smin[curb * 3 + 0], m0);
                atomicMin(&smin[curb * 3 + 1], m1);
                atomicMin(&smin[curb * 3 + 2], m2);
            }
            curb = b; m0 = m1 = m2 = 0x7FFFFFFF;
        }
        m0 = min(m0, __float_as_int(coord[(size_t)i * 3 + 0]));
        m1 = min(m1, __float_as_int(coord[(size_t)i * 3 + 1]));
        m2 = min(m2, __float_as_int(coord[(size_t)i * 3 + 2]));
    }
    if (curb >= 0) {
        atomicMin(&smin[curb * 3 + 0], m0);
        atomicMin(&smin[curb * 3 + 1], m1);
        atomicMin(&smin[curb * 3 + 2], m2);
    }
    __syncthreads();
    if (t < B * 3 && smin[t] != 0x7FFFFFFF) atomicMin(&startEnc[t], smin[t]);
}

// ---------- per-point voxel key + histogram + RANK (packed int2 store) ----------
// The histogram atomic's RETURN VALUE is the point's rank within its voxel.
// vr[i] = {vkey, rank}: one 8 B store here, one 8 B load in k_scat.
__global__ void k_count(const float* __restrict__ coord, const int* __restrict__ offset,
                        const int* __restrict__ startEnc, const float* __restrict__ gsP,
                        int* counts, int2* __restrict__ vr, int N, int B) {
    int i = blockIdx.x * blockDim.x + threadIdx.x;
    if (i >= N) return;
    float inv_gs = 1.0f / gsP[0];
    int b = batch_of(i, offset, B);
    float s0 = __int_as_float(startEnc[b * 3 + 0]);
    float s1 = __int_as_float(startEnc[b * 3 + 1]);
    float s2 = __int_as_float(startEnc[b * 3 + 2]);
    int vx = min(DGRID - 1, (int)floorf((coord[(size_t)i * 3 + 0] - s0) * inv_gs));
    int vy = min(DGRID - 1, (int)floorf((coord[(size_t)i * 3 + 1] - s1) * inv_gs));
    int vz = min(DGRID - 1, (int)floorf((coord[(size_t)i * 3 + 2] - s2) * inv_gs));
    int k = ((b * DGRID + vx) * DGRID + vy) * DGRID + vz;
    int r = atomicAdd(&counts[k], 1);                         // rank within voxel, free
    vr[i] = make_int2(k, r);
}

// ---------- scan pass 1: per-chunk (1024 keys) totals ----------
__global__ void k_scan1(const int* __restrict__ counts, int* occPart, int* cntPart, int KSM) {
    __shared__ int so[256], sc[256];
    int t = threadIdx.x;
    int base = blockIdx.x * 1024 + t * 4;
    int o = 0, c = 0;
    for (int r = 0; r < 4; ++r) {
        int k = base + r;
        if (k < KSM) { int cnt = counts[k]; o += (cnt > 0); c += cnt; }
    }
    so[t] = o; sc[t] = c;
    __syncthreads();
    for (int s = 128; s > 0; s >>= 1) {
        if (t < s) { so[t] += so[t + s]; sc[t] += sc[t + s]; }
        __syncthreads();
    }
    if (t == 0) { occPart[blockIdx.x] = so[0]; cntPart[blockIdx.x] = sc[0]; }
}

// ---------- scan pass 3 (pass 2 folded in): full exclusive scans -> krec + cluster tables ----------
// krec[k] = int2{occScan (cluster idx), cntScan (slot base)}: read-only
// downstream, lines stay shared across XCD L2s (no invalidations).
__global__ void k_scan3(const int* __restrict__ counts,
                        const int* __restrict__ occPart, const int* __restrict__ cntPart,
                        int2* krec, int* cntC, int* cstartC, int KSM, int NBLK) {
    __shared__ int so[256], sc[256];
    __shared__ int po[128], pc[128];
    __shared__ int poEx, pcEx;
    int t = threadIdx.x;

    // fold of former k_scan2: inclusive scan of block partials in LDS
    if (t < 128) {
        po[t] = (t < NBLK) ? occPart[t] : 0;
        pc[t] = (t < NBLK) ? cntPart[t] : 0;
    }
    __syncthreads();
    for (int s = 1; s < 128; s <<= 1) {
        int ao = 0, ac = 0;
        if (t < 128 && t >= s) { ao = po[t - s]; ac = pc[t - s]; }
        __syncthreads();
        if (t < 128) { po[t] += ao; pc[t] += ac; }
        __syncthreads();
    }
    if (t == 0) {
        int b = blockIdx.x;
        poEx = (b == 0) ? 0 : po[b - 1];
        pcEx = (b == 0) ? 0 : pc[b - 1];
    }
    __syncthreads();

    // original pass 3 body
    int base = blockIdx.x * 1024 + t * 4;
    int o[4], c[4];
    int tO = 0, tC = 0;
    for (int r = 0; r < 4; ++r) {
        int k = base + r;
        int cnt = (k < KSM) ? counts[k] : 0;
        o[r] = (cnt > 0); c[r] = cnt;
        tO += o[r]; tC += c[r];
    }
    so[t] = tO; sc[t] = tC;
    __syncthreads();
    for (int s = 1; s < 256; s <<= 1) {
        int ao = 0, ac = 0;
        if (t >= s) { ao = so[t - s]; ac = sc[t - s]; }
        __syncthreads();
        so[t] += ao; sc[t] += ac;
        __syncthreads();
    }
    int exO = so[t] - tO + poEx;
    int exC = sc[t] - tC + pcEx;
    for (int r = 0; r < 4; ++r) {
        int k = base + r;
        if (k < KSM) {
            krec[k] = make_int2(exO, exC);
            if (c[r] > 0) { cntC[exO] = c[r]; cstartC[exO] = exC; }
            exO += o[r]; exC += c[r];
        }
    }
}

// ---------- fused slot-assign + payload scatter, ATOMIC-FREE ----------
// Ledger evidence (R2/R4/R5): scattered 64 B payload writes are ~free when not
// serialized behind an atomic; the expensive variant was the random 128 B READ
// gather (k_mat, 82 us). So: read everything COALESCED on the source side
// (vr, feat, coord), one random read-only 8 B krec probe (L2-hot, 4.7 MB),
// pos = base + rank (pure arithmetic), write payload SCATTERED (fire-and-
// forget). No plist, one fewer kernel, no 108 MB random fetch.
__global__ void k_scat(const int2* __restrict__ vr, const int2* __restrict__ krec,
                       const float* __restrict__ feat, const float* __restrict__ coord,
                       short* __restrict__ featR, float* __restrict__ coordR,
                       float* __restrict__ dout, int N, int B, int M) {
    int i = blockIdx.x * blockDim.x + threadIdx.x;
    if (i >= N) return;
    int2 v = vr[i];                                           // {vkey, rank}, coalesced 8 B
    int2 rec = krec[v.x];                                     // read-only random 8 B (L2-hot)
    int pos = rec.y + v.y;
    dout[(size_t)67 * M + B + i] = (float)rec.x;              // inverse (coalesced)

    const float4* fp = reinterpret_cast<const float4*>(feat + (size_t)i * 32);
    bf16x8* dst = reinterpret_cast<bf16x8*>(featR + (size_t)pos * 32);
#pragma unroll
    for (int t = 0; t < 4; ++t) {
        float4 a = fp[2 * t];                                 // coalesced 128 B/row read
        float4 b2 = fp[2 * t + 1];
        bf16x8 r;
        r[0] = f2bf(a.x);  r[1] = f2bf(a.y);  r[2] = f2bf(a.z);  r[3] = f2bf(a.w);
        r[4] = f2bf(b2.x); r[5] = f2bf(b2.y); r[6] = f2bf(b2.z); r[7] = f2bf(b2.w);
        dst[t] = r;                                           // scattered 16 B store
    }
    float4 cv;
    cv.x = coord[(size_t)i * 3 + 0];
    cv.y = coord[(size_t)i * 3 + 1];
    cv.z = coord[(size_t)i * 3 + 2];
    cv.w = 0.f;
    *reinterpret_cast<float4*>(coordR + (size_t)pos * 4) = cv; // scattered 16 B store
}

// ---------- fused MLP + segment-max via MFMA: one wave/block, TWO ADJACENT clusters/iter ----------
// featR rows are cluster-contiguous: a wave reads 16 rows x 64 B = 1 KB contiguous
// per cluster per K-step (one dwordx4/lane), and the paired cluster's block is
// adjacent. Max needs NO masking (pad rows replicate a real point via clamped idx);
// stats masked by row<cnt (and by has2 for the duplicated second cluster).
// Coord mean: quads 1..3 read component quad-1 from coordR, reduce within quad.
__launch_bounds__(64)
__global__ void k_pool(const short* __restrict__ featR, const float* __restrict__ coordR,
                       const float* __restrict__ W,
                       const int* __restrict__ cstartC, const int* __restrict__ cntC,
                       float* __restrict__ dout, float* __restrict__ statPart, int M) {
    const int lane = threadIdx.x;
    const int col  = lane & 15;
    const int quad = lane >> 4;
    const int nw = gridDim.x;
    const int gw = blockIdx.x;

    bf16x8 Bf[4];
#pragma unroll
    for (int t = 0; t < 4; ++t) {
#pragma unroll
        for (int j = 0; j < 8; ++j) {
            int k = quad * 8 + j;
            Bf[t][j] = f2bf(W[k * 64 + t * 16 + col]);
        }
    }

    float sumA[4] = {0.f, 0.f, 0.f, 0.f};
    float sqA[4]  = {0.f, 0.f, 0.f, 0.f};

    for (int c0 = 2 * gw; c0 < M; c0 += 2 * nw) {
        int c1 = c0 + 1;
        bool has2 = (c1 < M);
        if (!has2) c1 = c0;
        int ps0 = cstartC[c0], n0 = cntC[c0];       // uniform per wave
        int ps1 = cstartC[c1], n1 = cntC[c1];
        int nmax = max(n0, n1);

        float maxA0[4] = {-FLT_MAX, -FLT_MAX, -FLT_MAX, -FLT_MAX};
        float maxA1[4] = {-FLT_MAX, -FLT_MAX, -FLT_MAX, -FLT_MAX};
        float cacc0 = 0.f, cacc1 = 0.f;             // coord component quad-1 (quads 1..3)

        for (int base = 0; base < nmax; base += 16) {
            int m = base + col;
            int idx0 = min(m, n0 - 1);              // clamp: replicate last real row
            int idx1 = min(m, n1 - 1);
            bf16x8 Af0 = *reinterpret_cast<const bf16x8*>(featR + (size_t)(ps0 + idx0) * 32 + quad * 8);
            bf16x8 Af1 = *reinterpret_cast<const bf16x8*>(featR + (size_t)(ps1 + idx1) * 32 + quad * 8);
            if (quad > 0) {                         // coord: quads 1..3 load comp quad-1
                float v0 = coordR[(size_t)(ps0 + idx0) * 4 + (quad - 1)];
                float v1 = coordR[(size_t)(ps1 + idx1) * 4 + (quad - 1)];
                cacc0 += (m < n0) ? v0 : 0.f;
                cacc1 += (m < n1) ? v1 : 0.f;
            }
            f32x4 Cz = {0.f, 0.f, 0.f, 0.f};
#pragma unroll
            for (int t = 0; t < 4; ++t) {
                f32x4 v0 = __builtin_amdgcn_mfma_f32_16x16x32_bf16(Af0, Bf[t], Cz, 0, 0, 0);
                f32x4 v1 = __builtin_amdgcn_mfma_f32_16x16x32_bf16(Af1, Bf[t], Cz, 0, 0, 0);
#pragma unroll
                for (int r = 0; r < 4; ++r) {
                    int rowPt = base + quad * 4 + r;
                    maxA0[t] = fmaxf(maxA0[t], v0[r]);          // replication-safe, no mask
                    maxA1[t] = fmaxf(maxA1[t], v1[r]);
                    float m0 = (rowPt < n0) ? v0[r] : 0.f;
                    sumA[t] += m0; sqA[t] = fmaf(m0, m0, sqA[t]);
                    float m1 = (rowPt < n1 && has2) ? v1[r] : 0.f;
                    sumA[t] += m1; sqA[t] = fmaf(m1, m1, sqA[t]);
                }
            }
        }
        // per-channel max writes (duplicate write for !has2 is benign)
        float out0 = 0.f, out1 = 0.f;
#pragma unroll
        for (int t = 0; t < 4; ++t) {
            float v = maxA0[t];
            v = fmaxf(v, __shfl_xor(v, 16, 64));
            v = fmaxf(v, __shfl_xor(v, 32, 64));
            if (quad == t) out0 = v;
            float w = maxA1[t];
            w = fmaxf(w, __shfl_xor(w, 16, 64));
            w = fmaxf(w, __shfl_xor(w, 32, 64));
            if (quad == t) out1 = w;
        }
        dout[(size_t)3 * M + (size_t)c0 * 64 + lane] = out0;
        dout[(size_t)3 * M + (size_t)c1 * 64 + lane] = out1;

        // coord means: reduce within quad (cols), col-0 of quads 1..3 writes comp quad-1
        cacc0 += __shfl_xor(cacc0, 1, 64); cacc0 += __shfl_xor(cacc0, 2, 64);
        cacc0 += __shfl_xor(cacc0, 4, 64); cacc0 += __shfl_xor(cacc0, 8, 64);
        cacc1 += __shfl_xor(cacc1, 1, 64); cacc1 += __shfl_xor(cacc1, 2, 64);
        cacc1 += __shfl_xor(cacc1, 4, 64); cacc1 += __shfl_xor(cacc1, 8, 64);
        if (quad > 0 && col == 0) {
            dout[(size_t)c0 * 3 + (quad - 1)] = cacc0 / (float)n0;
            dout[(size_t)c1 * 3 + (quad - 1)] = cacc1 / (float)n1;
        }
    }

    float so = 0.f, qo = 0.f;
#pragma unroll
    for (int t = 0; t < 4; ++t) {
        float s = sumA[t];
        s += __shfl_xor(s, 16, 64);
        s += __shfl_xor(s, 32, 64);
        float q = sqA[t];
        q += __shfl_xor(q, 16, 64);
        q += __shfl_xor(q, 32, 64);
        if (quad == t) { so = s; qo = q; }
    }
    statPart[(size_t)gw * 128 + lane] = so;
    statPart[(size_t)gw * 128 + 64 + lane] = qo;
}

// ---------- reduce stat partials -> BN params (one block per channel) ----------
__global__ void k_statred(const float* __restrict__ statPart,
                          const float* __restrict__ gamma, const float* __restrict__ beta,
                          float* bnA, float* bnB, int NB, int N) {
    __shared__ float s1[256], s2[256];
    int c = blockIdx.x;
    int t = threadIdx.x;
    float a = 0.f, b = 0.f;
    for (int bb = t; bb < NB; bb += 256) {
        a += statPart[(size_t)bb * 128 + c];
        b += statPart[(size_t)bb * 128 + 64 + c];
    }
    s1[t] = a; s2[t] = b;
    __syncthreads();
    for (int s = 128; s > 0; s >>= 1) {
        if (t < s) { s1[t] += s1[t + s]; s2[t] += s2[t + s]; }
        __syncthreads();
    }
    if (t == 0) {
        float invN = 1.0f / (float)N;
        float mean = s1[0] * invN;
        float var = s2[0] * invN - mean * mean;
        float aa = gamma[c] / sqrtf(var + EPSV);
        bnA[c] = aa;
        bnB[c] = beta[c] - mean * aa;
    }
}

// ---------- finalize: BN+ReLU on maxima, offset_out ----------
__global__ void k_final(float* __restrict__ dout, const float* __restrict__ bnA,
                        const float* __restrict__ bnB,
                        const int2* __restrict__ krec, int M, int B) {
    size_t stride = (size_t)gridDim.x * blockDim.x;
    size_t tid0 = (size_t)blockIdx.x * blockDim.x + threadIdx.x;
    size_t totF = (size_t)M * 64;
    for (size_t t = tid0; t < totF; t += stride) {
        int c = (int)(t & 63);
        float v = dout[(size_t)3 * M + t];
        dout[(size_t)3 * M + t] = fmaxf(bnA[c] * v + bnB[c], 0.f);
    }
    if (tid0 < (size_t)B) {
        int val = (tid0 == (size_t)(B - 1)) ? M : krec[(size_t)(tid0 + 1) * DPROD].x;
        dout[(size_t)67 * M + tid0] = (float)val;
    }
}

extern "C" void kernel_launch(void* const* d_in, const int* in_sizes, int n_in,
                              void* d_out, int out_size, void* d_ws, size_t ws_size,
                              hipStream_t stream) {
    const float* coord = (const float*)d_in[0];
    const float* feat  = (const float*)d_in[1];
    const int*   offset = (const int*)d_in[2];
    const float* W     = (const float*)d_in[3];
    const float* gamma = (const float*)d_in[4];
    const float* beta  = (const float*)d_in[5];
    const float* gsP   = (const float*)d_in[6];
    float* dout = (float*)d_out;

    const int N = in_sizes[0] / 3;
    const int B = in_sizes[2];
    const int M = (out_size - B - N) / 67;         // dout layout fixes M
    const int KSM = B * DPROD;                     // conservative keyspace, order-preserving
    const int NBLK = (KSM + 1023) / 1024;          // scan chunks (<=128)
    const int NBPL = 8192;                         // k_pool single-wave blocks

    // workspace layout (int units)
    int* wsI = (int*)d_ws;
    int* startEnc  = wsI + 0;                // B*3
    float* bnA     = (float*)(wsI + 64);     // 64
    float* bnB     = (float*)(wsI + 128);    // 64
    int* occPart   = wsI + 256;              // 128
    int* cntPart   = wsI + 384;              // 128
    int* counts    = wsI + 1024;             // KSM
    int2* krec     = (int2*)(counts + KSM);  // KSM int2 (8 B each; 1024+KSM even -> aligned)
    int* cntC      = (int*)(krec + KSM);     // KSM (>= M)
    int* cstartC   = cntC + KSM;             // KSM (>= M)
    int2* vr       = (int2*)(cstartC + KSM); // N int2 {vkey, rank} (even offset -> aligned)
    float* statPart = (float*)(vr + N);      // NBPL*128 floats
    short* featR   = (short*)(statPart + (size_t)NBPL * 128);  // N*32 bf16 (64 MB)
    float* coordR  = (float*)(featR + (size_t)N * 32);         // N*4 floats (16 MB)

    const int TPB = 256;
    int gChunk = (N + 1023) / 1024;
    int gPoint = (N + TPB - 1) / TPB;

    k_init<<<1, 64, 0, stream>>>(startEnc, B);
    k_start<<<gChunk, TPB, 0, stream>>>(coord, offset, startEnc, counts, KSM, N, B);
    k_count<<<gPoint, TPB, 0, stream>>>(coord, offset, startEnc, gsP, counts, vr, N, B);
    k_scan1<<<NBLK, TPB, 0, stream>>>(counts, occPart, cntPart, KSM);
    k_scan3<<<NBLK, TPB, 0, stream>>>(counts, occPart, cntPart, krec, cntC, cstartC, KSM, NBLK);
    k_scat<<<gPoint, TPB, 0, stream>>>(vr, krec, feat, coord, featR, coordR, dout, N, B, M);
    k_pool<<<NBPL, 64, 0, stream>>>(featR, coordR, W, cstartC, cntC, dout, statPart, M);
    k_statred<<<64, 256, 0, stream>>>(statPart, gamma, beta, bnA, bnB, NBPL, N);
    k_final<<<1024, TPB, 0, stream>>>(dout, bnA, bnB, krec, M, B);
}

// Round 12
// 348.222 us; speedup vs baseline: 1.1364x; 1.1364x over previous
//
#include <hip/hip_runtime.h>
#include <float.h>

#define EPSV 1e-5f
#define DGRID 21
#define DPROD (21 * 21 * 21)

typedef __attribute__((ext_vector_type(8))) short bf16x8;
typedef __attribute__((ext_vector_type(4))) float f32x4;

// fp32 -> bf16 (RNE), bit pattern in short
__device__ __forceinline__ short f2bf(float x) {
    unsigned u = __float_as_uint(x);
    unsigned r = (u + 0x7FFFu + ((u >> 16) & 1u)) >> 16;
    return (short)r;
}

// ---------- helpers ----------
__device__ __forceinline__ int batch_of(int i, const int* __restrict__ offset, int B) {
    int b = 0;
    while (b < B - 1 && i >= offset[b]) ++b;
    return b;
}

// ---------- init: startEnc only (must complete before k_start's atomicMin) ----------
__global__ void k_init(int* startEnc, int B) {
    int tid = threadIdx.x;
    if (tid < B * 3) startEnc[tid] = 0x7FFFFFFF;              // +inf for non-neg floats
}

// ---------- per-batch coord min (segment_min) + counts zeroing ----------
__global__ void k_start(const float* __restrict__ coord, const int* __restrict__ offset,
                        int* startEnc, int* counts, int KSM, int N, int B) {
    int gtid = blockIdx.x * blockDim.x + threadIdx.x;
    for (int k = gtid; k < KSM; k += gridDim.x * blockDim.x) counts[k] = 0;

    __shared__ int smin[24];
    int t = threadIdx.x;
    if (t < B * 3) smin[t] = 0x7FFFFFFF;
    __syncthreads();
    int base = gtid * 4;
    int curb = -1;
    int m0 = 0x7FFFFFFF, m1 = 0x7FFFFFFF, m2 = 0x7FFFFFFF;
    for (int r = 0; r < 4; ++r) {
        int i = base + r;
        if (i >= N) break;
        int b = batch_of(i, offset, B);
        if (b != curb) {
            if (curb >= 0) {
                atomicMin(&smin[curb * 3 + 0], m0);
                atomicMin(&smin[curb * 3 + 1], m1);
                atomicMin(&smin[curb * 3 + 2], m2);
            }
            curb = b; m0 = m1 = m2 = 0x7FFFFFFF;
        }
        m0 = min(m0, __float_as_int(coord[(size_t)i * 3 + 0]));
        m1 = min(m1, __float_as_int(coord[(size_t)i * 3 + 1]));
        m2 = min(m2, __float_as_int(coord[(size_t)i * 3 + 2]));
    }
    if (curb >= 0) {
        atomicMin(&smin[curb * 3 + 0], m0);
        atomicMin(&smin[curb * 3 + 1], m1);
        atomicMin(&smin[curb * 3 + 2], m2);
    }
    __syncthreads();
    if (t < B * 3 && smin[t] != 0x7FFFFFFF) atomicMin(&startEnc[t], smin[t]);
}

// ---------- per-point voxel key + histogram + RANK (packed int2 store) ----------
// The histogram atomic's RETURN VALUE is the point's rank within its voxel.
__global__ void k_count(const float* __restrict__ coord, const int* __restrict__ offset,
                        const int* __restrict__ startEnc, const float* __restrict__ gsP,
                        int* counts, int2* __restrict__ vr, int N, int B) {
    int i = blockIdx.x * blockDim.x + threadIdx.x;
    if (i >= N) return;
    float inv_gs = 1.0f / gsP[0];
    int b = batch_of(i, offset, B);
    float s0 = __int_as_float(startEnc[b * 3 + 0]);
    float s1 = __int_as_float(startEnc[b * 3 + 1]);
    float s2 = __int_as_float(startEnc[b * 3 + 2]);
    int vx = min(DGRID - 1, (int)floorf((coord[(size_t)i * 3 + 0] - s0) * inv_gs));
    int vy = min(DGRID - 1, (int)floorf((coord[(size_t)i * 3 + 1] - s1) * inv_gs));
    int vz = min(DGRID - 1, (int)floorf((coord[(size_t)i * 3 + 2] - s2) * inv_gs));
    int k = ((b * DGRID + vx) * DGRID + vy) * DGRID + vz;
    int r = atomicAdd(&counts[k], 1);                         // rank within voxel, free
    vr[i] = make_int2(k, r);
}

// ---------- scan pass 1: per-chunk (1024 keys) totals ----------
__global__ void k_scan1(const int* __restrict__ counts, int* occPart, int* cntPart, int KSM) {
    __shared__ int so[256], sc[256];
    int t = threadIdx.x;
    int base = blockIdx.x * 1024 + t * 4;
    int o = 0, c = 0;
    for (int r = 0; r < 4; ++r) {
        int k = base + r;
        if (k < KSM) { int cnt = counts[k]; o += (cnt > 0); c += cnt; }
    }
    so[t] = o; sc[t] = c;
    __syncthreads();
    for (int s = 128; s > 0; s >>= 1) {
        if (t < s) { so[t] += so[t + s]; sc[t] += sc[t + s]; }
        __syncthreads();
    }
    if (t == 0) { occPart[blockIdx.x] = so[0]; cntPart[blockIdx.x] = sc[0]; }
}

// ---------- scan pass 3 (pass 2 folded in): full exclusive scans -> krec + cluster tables ----------
// krec[k] = int2{occScan (cluster idx), cntScan (slot base)}: read-only downstream.
__global__ void k_scan3(const int* __restrict__ counts,
                        const int* __restrict__ occPart, const int* __restrict__ cntPart,
                        int2* krec, int* cntC, int* cstartC, int KSM, int NBLK) {
    __shared__ int so[256], sc[256];
    __shared__ int po[128], pc[128];
    __shared__ int poEx, pcEx;
    int t = threadIdx.x;

    // fold of former k_scan2: inclusive scan of block partials in LDS
    if (t < 128) {
        po[t] = (t < NBLK) ? occPart[t] : 0;
        pc[t] = (t < NBLK) ? cntPart[t] : 0;
    }
    __syncthreads();
    for (int s = 1; s < 128; s <<= 1) {
        int ao = 0, ac = 0;
        if (t < 128 && t >= s) { ao = po[t - s]; ac = pc[t - s]; }
        __syncthreads();
        if (t < 128) { po[t] += ao; pc[t] += ac; }
        __syncthreads();
    }
    if (t == 0) {
        int b = blockIdx.x;
        poEx = (b == 0) ? 0 : po[b - 1];
        pcEx = (b == 0) ? 0 : pc[b - 1];
    }
    __syncthreads();

    // original pass 3 body
    int base = blockIdx.x * 1024 + t * 4;
    int o[4], c[4];
    int tO = 0, tC = 0;
    for (int r = 0; r < 4; ++r) {
        int k = base + r;
        int cnt = (k < KSM) ? counts[k] : 0;
        o[r] = (cnt > 0); c[r] = cnt;
        tO += o[r]; tC += c[r];
    }
    so[t] = tO; sc[t] = tC;
    __syncthreads();
    for (int s = 1; s < 256; s <<= 1) {
        int ao = 0, ac = 0;
        if (t >= s) { ao = so[t - s]; ac = sc[t - s]; }
        __syncthreads();
        so[t] += ao; sc[t] += ac;
        __syncthreads();
    }
    int exO = so[t] - tO + poEx;
    int exC = sc[t] - tC + pcEx;
    for (int r = 0; r < 4; ++r) {
        int k = base + r;
        if (k < KSM) {
            krec[k] = make_int2(exO, exC);
            if (c[r] > 0) { cntC[exO] = c[r]; cstartC[exO] = exC; }
            exO += o[r]; exC += c[r];
        }
    }
}

// ---------- slot assignment, ATOMIC-FREE (21 us proven, R5) ----------
// pos = krec[k].y + rank; krec read-only (L2-shared, no ping-pong).
__global__ void k_pos(const int2* __restrict__ vr, const int2* __restrict__ krec,
                      int* __restrict__ plist, float* __restrict__ dout,
                      int N, int B, int M) {
    int i = blockIdx.x * blockDim.x + threadIdx.x;
    if (i >= N) return;
    int2 v = vr[i];                                           // {vkey, rank}, one 8 B
    int2 rec = krec[v.x];                                     // read-only random 8 B
    plist[rec.y + v.y] = i;                                   // 4 B scattered
    dout[(size_t)67 * M + B + i] = (float)rec.x;              // inverse (coalesced)
}

// ---------- fused MLP + segment-max via MFMA: GATHER version (R0-proven) ----------
// Ledger A/B (R0-input vs R2, only k_pool's input side differs): gather-pool
// == contiguous-pool within 1 us — 8192 single-wave blocks of TLP hide the
// plist->feat gather latency and the f2bf conversions completely. So the
// payload permutation pass (~82-104 us) bought nothing; it is deleted.
// plist reads are CONTIGUOUS within a cluster; feat rows are single 128 B
// lines. Max needs no masking (pad rows replicate a real point); stats
// masked by row<cnt (and has2). Two independent gather chains in flight.
__launch_bounds__(64)
__global__ void k_pool(const float* __restrict__ feat, const float* __restrict__ coord,
                       const float* __restrict__ W,
                       const int* __restrict__ cstartC, const int* __restrict__ cntC,
                       const int* __restrict__ plist,
                       float* __restrict__ dout, float* __restrict__ statPart, int M) {
    const int lane = threadIdx.x;
    const int col  = lane & 15;
    const int quad = lane >> 4;
    const int nw = gridDim.x;
    const int gw = blockIdx.x;

    bf16x8 Bf[4];
#pragma unroll
    for (int t = 0; t < 4; ++t) {
#pragma unroll
        for (int j = 0; j < 8; ++j) {
            int k = quad * 8 + j;
            Bf[t][j] = f2bf(W[k * 64 + t * 16 + col]);
        }
    }

    float sumA[4] = {0.f, 0.f, 0.f, 0.f};
    float sqA[4]  = {0.f, 0.f, 0.f, 0.f};

    for (int c0 = gw; c0 < M; c0 += 2 * nw) {
        int c1 = c0 + nw;
        bool has2 = c1 < M;
        if (!has2) c1 = c0;
        int ps0 = cstartC[c0], n0 = cntC[c0];       // uniform -> s_load
        int ps1 = cstartC[c1], n1 = cntC[c1];
        int nmax = max(n0, n1);

        float maxA0[4] = {-FLT_MAX, -FLT_MAX, -FLT_MAX, -FLT_MAX};
        float maxA1[4] = {-FLT_MAX, -FLT_MAX, -FLT_MAX, -FLT_MAX};
        float cacc0 = 0.f, cacc1 = 0.f;             // coord component quad-1 (quads 1..3)

        for (int base = 0; base < nmax; base += 16) {
            int m = base + col;
            int idx0 = min(m, n0 - 1);
            int idx1 = min(m, n1 - 1);
            int p0 = plist[ps0 + idx0];             // two independent gather chains
            int p1 = plist[ps1 + idx1];
            const float4* r0p = reinterpret_cast<const float4*>(feat + (size_t)p0 * 32 + quad * 8);
            const float4* r1p = reinterpret_cast<const float4*>(feat + (size_t)p1 * 32 + quad * 8);
            float4 a00 = r0p[0], a01 = r0p[1];
            float4 a10 = r1p[0], a11 = r1p[1];
            if (quad > 0) {                         // coord: quads 1..3 load comp quad-1
                float v0 = coord[(size_t)p0 * 3 + (quad - 1)];
                float v1 = coord[(size_t)p1 * 3 + (quad - 1)];
                cacc0 += (m < n0) ? v0 : 0.f;
                cacc1 += (m < n1) ? v1 : 0.f;
            }
            bf16x8 Af0, Af1;
            Af0[0] = f2bf(a00.x); Af0[1] = f2bf(a00.y); Af0[2] = f2bf(a00.z); Af0[3] = f2bf(a00.w);
            Af0[4] = f2bf(a01.x); Af0[5] = f2bf(a01.y); Af0[6] = f2bf(a01.z); Af0[7] = f2bf(a01.w);
            Af1[0] = f2bf(a10.x); Af1[1] = f2bf(a10.y); Af1[2] = f2bf(a10.z); Af1[3] = f2bf(a10.w);
            Af1[4] = f2bf(a11.x); Af1[5] = f2bf(a11.y); Af1[6] = f2bf(a11.z); Af1[7] = f2bf(a11.w);
            f32x4 Cz = {0.f, 0.f, 0.f, 0.f};
#pragma unroll
            for (int t = 0; t < 4; ++t) {
                f32x4 v0 = __builtin_amdgcn_mfma_f32_16x16x32_bf16(Af0, Bf[t], Cz, 0, 0, 0);
                f32x4 v1 = __builtin_amdgcn_mfma_f32_16x16x32_bf16(Af1, Bf[t], Cz, 0, 0, 0);
#pragma unroll
                for (int r = 0; r < 4; ++r) {
                    int rowPt = base + quad * 4 + r;
                    maxA0[t] = fmaxf(maxA0[t], v0[r]);          // replication-safe, no mask
                    maxA1[t] = fmaxf(maxA1[t], v1[r]);
                    float m0 = (rowPt < n0) ? v0[r] : 0.f;
                    sumA[t] += m0; sqA[t] = fmaf(m0, m0, sqA[t]);
                    float m1 = (rowPt < n1 && has2) ? v1[r] : 0.f;
                    sumA[t] += m1; sqA[t] = fmaf(m1, m1, sqA[t]);
                }
            }
        }
        // per-channel max writes (duplicate write for !has2 is benign)
        float out0 = 0.f, out1 = 0.f;
#pragma unroll
        for (int t = 0; t < 4; ++t) {
            float v = maxA0[t];
            v = fmaxf(v, __shfl_xor(v, 16, 64));
            v = fmaxf(v, __shfl_xor(v, 32, 64));
            if (quad == t) out0 = v;
            float w = maxA1[t];
            w = fmaxf(w, __shfl_xor(w, 16, 64));
            w = fmaxf(w, __shfl_xor(w, 32, 64));
            if (quad == t) out1 = w;
        }
        dout[(size_t)3 * M + (size_t)c0 * 64 + lane] = out0;
        dout[(size_t)3 * M + (size_t)c1 * 64 + lane] = out1;

        // coord means: reduce within quad (cols), col-0 of quads 1..3 writes comp quad-1
        cacc0 += __shfl_xor(cacc0, 1, 64); cacc0 += __shfl_xor(cacc0, 2, 64);
        cacc0 += __shfl_xor(cacc0, 4, 64); cacc0 += __shfl_xor(cacc0, 8, 64);
        cacc1 += __shfl_xor(cacc1, 1, 64); cacc1 += __shfl_xor(cacc1, 2, 64);
        cacc1 += __shfl_xor(cacc1, 4, 64); cacc1 += __shfl_xor(cacc1, 8, 64);
        if (quad > 0 && col == 0) {
            dout[(size_t)c0 * 3 + (quad - 1)] = cacc0 / (float)n0;
            dout[(size_t)c1 * 3 + (quad - 1)] = cacc1 / (float)n1;
        }
    }

    float so = 0.f, qo = 0.f;
#pragma unroll
    for (int t = 0; t < 4; ++t) {
        float s = sumA[t];
        s += __shfl_xor(s, 16, 64);
        s += __shfl_xor(s, 32, 64);
        float q = sqA[t];
        q += __shfl_xor(q, 16, 64);
        q += __shfl_xor(q, 32, 64);
        if (quad == t) { so = s; qo = q; }
    }
    statPart[(size_t)gw * 128 + lane] = so;
    statPart[(size_t)gw * 128 + 64 + lane] = qo;
}

// ---------- reduce stat partials -> BN params (one block per channel) ----------
__global__ void k_statred(const float* __restrict__ statPart,
                          const float* __restrict__ gamma, const float* __restrict__ beta,
                          float* bnA, float* bnB, int NB, int N) {
    __shared__ float s1[256], s2[256];
    int c = blockIdx.x;
    int t = threadIdx.x;
    float a = 0.f, b = 0.f;
    for (int bb = t; bb < NB; bb += 256) {
        a += statPart[(size_t)bb * 128 + c];
        b += statPart[(size_t)bb * 128 + 64 + c];
    }
    s1[t] = a; s2[t] = b;
    __syncthreads();
    for (int s = 128; s > 0; s >>= 1) {
        if (t < s) { s1[t] += s1[t + s]; s2[t] += s2[t + s]; }
        __syncthreads();
    }
    if (t == 0) {
        float invN = 1.0f / (float)N;
        float mean = s1[0] * invN;
        float var = s2[0] * invN - mean * mean;
        float aa = gamma[c] / sqrtf(var + EPSV);
        bnA[c] = aa;
        bnB[c] = beta[c] - mean * aa;
    }
}

// ---------- finalize: BN+ReLU on maxima, offset_out ----------
__global__ void k_final(float* __restrict__ dout, const float* __restrict__ bnA,
                        const float* __restrict__ bnB,
                        const int2* __restrict__ krec, int M, int B) {
    size_t stride = (size_t)gridDim.x * blockDim.x;
    size_t tid0 = (size_t)blockIdx.x * blockDim.x + threadIdx.x;
    size_t totF = (size_t)M * 64;
    for (size_t t = tid0; t < totF; t += stride) {
        int c = (int)(t & 63);
        float v = dout[(size_t)3 * M + t];
        dout[(size_t)3 * M + t] = fmaxf(bnA[c] * v + bnB[c], 0.f);
    }
    if (tid0 < (size_t)B) {
        int val = (tid0 == (size_t)(B - 1)) ? M : krec[(size_t)(tid0 + 1) * DPROD].x;
        dout[(size_t)67 * M + tid0] = (float)val;
    }
}

extern "C" void kernel_launch(void* const* d_in, const int* in_sizes, int n_in,
                              void* d_out, int out_size, void* d_ws, size_t ws_size,
                              hipStream_t stream) {
    const float* coord = (const float*)d_in[0];
    const float* feat  = (const float*)d_in[1];
    const int*   offset = (const int*)d_in[2];
    const float* W     = (const float*)d_in[3];
    const float* gamma = (const float*)d_in[4];
    const float* beta  = (const float*)d_in[5];
    const float* gsP   = (const float*)d_in[6];
    float* dout = (float*)d_out;

    const int N = in_sizes[0] / 3;
    const int B = in_sizes[2];
    const int M = (out_size - B - N) / 67;         // dout layout fixes M
    const int KSM = B * DPROD;                     // conservative keyspace, order-preserving
    const int NBLK = (KSM + 1023) / 1024;          // scan chunks (<=128)
    const int NBPL = 8192;                         // k_pool single-wave blocks

    // workspace layout (int units)
    int* wsI = (int*)d_ws;
    int* startEnc  = wsI + 0;                // B*3
    float* bnA     = (float*)(wsI + 64);     // 64
    float* bnB     = (float*)(wsI + 128);    // 64
    int* occPart   = wsI + 256;              // 128
    int* cntPart   = wsI + 384;              // 128
    int* counts    = wsI + 1024;             // KSM
    int2* krec     = (int2*)(counts + KSM);  // KSM int2 (8 B each; 1024+KSM even -> aligned)
    int* cntC      = (int*)(krec + KSM);     // KSM (>= M)
    int* cstartC   = cntC + KSM;             // KSM (>= M)
    int2* vr       = (int2*)(cstartC + KSM); // N int2 {vkey, rank} (even offset -> aligned)
    int* plist     = (int*)(vr + N);         // N
    float* statPart = (float*)(plist + N);   // NBPL*128 floats

    const int TPB = 256;
    int gChunk = (N + 1023) / 1024;
    int gPoint = (N + TPB - 1) / TPB;

    k_init<<<1, 64, 0, stream>>>(startEnc, B);
    k_start<<<gChunk, TPB, 0, stream>>>(coord, offset, startEnc, counts, KSM, N, B);
    k_count<<<gPoint, TPB, 0, stream>>>(coord, offset, startEnc, gsP, counts, vr, N, B);
    k_scan1<<<NBLK, TPB, 0, stream>>>(counts, occPart, cntPart, KSM);
    k_scan3<<<NBLK, TPB, 0, stream>>>(counts, occPart, cntPart, krec, cntC, cstartC, KSM, NBLK);
    k_pos<<<gPoint, TPB, 0, stream>>>(vr, krec, plist, dout, N, B, M);
    k_pool<<<NBPL, 64, 0, stream>>>(feat, coord, W, cstartC, cntC, plist, dout, statPart, M);
    k_statred<<<64, 256, 0, stream>>>(statPart, gamma, beta, bnA, bnB, NBPL, N);
    k_final<<<1024, TPB, 0, stream>>>(dout, bnA, bnB, krec, M, B);
}

// Round 13
// 341.077 us; speedup vs baseline: 1.1602x; 1.0209x over previous
//
#include <hip/hip_runtime.h>
#include <float.h>

#define EPSV 1e-5f
#define DGRID 21
#define DPROD (21 * 21 * 21)

typedef __attribute__((ext_vector_type(8))) short bf16x8;
typedef __attribute__((ext_vector_type(4))) float f32x4;

// fp32 -> bf16 (RNE), bit pattern in short
__device__ __forceinline__ short f2bf(float x) {
    unsigned u = __float_as_uint(x);
    unsigned r = (u + 0x7FFFu + ((u >> 16) & 1u)) >> 16;
    return (short)r;
}

// ---------- helpers ----------
__device__ __forceinline__ int batch_of(int i, const int* __restrict__ offset, int B) {
    int b = 0;
    while (b < B - 1 && i >= offset[b]) ++b;
    return b;
}

// ---------- init: startEnc only (must complete before k_start's atomicMin) ----------
__global__ void k_init(int* startEnc, int B) {
    int tid = threadIdx.x;
    if (tid < B * 3) startEnc[tid] = 0x7FFFFFFF;              // +inf for non-neg floats
}

// ---------- per-batch coord min (segment_min) + counts zeroing ----------
__global__ void k_start(const float* __restrict__ coord, const int* __restrict__ offset,
                        int* startEnc, int* counts, int KSM, int N, int B) {
    int gtid = blockIdx.x * blockDim.x + threadIdx.x;
    for (int k = gtid; k < KSM; k += gridDim.x * blockDim.x) counts[k] = 0;

    __shared__ int smin[24];
    int t = threadIdx.x;
    if (t < B * 3) smin[t] = 0x7FFFFFFF;
    __syncthreads();
    int base = gtid * 4;
    int curb = -1;
    int m0 = 0x7FFFFFFF, m1 = 0x7FFFFFFF, m2 = 0x7FFFFFFF;
    for (int r = 0; r < 4; ++r) {
        int i = base + r;
        if (i >= N) break;
        int b = batch_of(i, offset, B);
        if (b != curb) {
            if (curb >= 0) {
                atomicMin(&smin[curb * 3 + 0], m0);
                atomicMin(&smin[curb * 3 + 1], m1);
                atomicMin(&smin[curb * 3 + 2], m2);
            }
            curb = b; m0 = m1 = m2 = 0x7FFFFFFF;
        }
        m0 = min(m0, __float_as_int(coord[(size_t)i * 3 + 0]));
        m1 = min(m1, __float_as_int(coord[(size_t)i * 3 + 1]));
        m2 = min(m2, __float_as_int(coord[(size_t)i * 3 + 2]));
    }
    if (curb >= 0) {
        atomicMin(&smin[curb * 3 + 0], m0);
        atomicMin(&smin[curb * 3 + 1], m1);
        atomicMin(&smin[curb * 3 + 2], m2);
    }
    __syncthreads();
    if (t < B * 3 && smin[t] != 0x7FFFFFFF) atomicMin(&startEnc[t], smin[t]);
}

// ---------- per-point voxel key + histogram + RANK (packed int2 store) ----------
// The histogram atomic's RETURN VALUE is the point's rank within its voxel.
__global__ void k_count(const float* __restrict__ coord, const int* __restrict__ offset,
                        const int* __restrict__ startEnc, const float* __restrict__ gsP,
                        int* counts, int2* __restrict__ vr, int N, int B) {
    int i = blockIdx.x * blockDim.x + threadIdx.x;
    if (i >= N) return;
    float inv_gs = 1.0f / gsP[0];
    int b = batch_of(i, offset, B);
    float s0 = __int_as_float(startEnc[b * 3 + 0]);
    float s1 = __int_as_float(startEnc[b * 3 + 1]);
    float s2 = __int_as_float(startEnc[b * 3 + 2]);
    int vx = min(DGRID - 1, (int)floorf((coord[(size_t)i * 3 + 0] - s0) * inv_gs));
    int vy = min(DGRID - 1, (int)floorf((coord[(size_t)i * 3 + 1] - s1) * inv_gs));
    int vz = min(DGRID - 1, (int)floorf((coord[(size_t)i * 3 + 2] - s2) * inv_gs));
    int k = ((b * DGRID + vx) * DGRID + vy) * DGRID + vz;
    int r = atomicAdd(&counts[k], 1);                         // rank within voxel, free
    vr[i] = make_int2(k, r);
}

// ---------- scan pass 1: per-chunk (1024 keys) totals ----------
__global__ void k_scan1(const int* __restrict__ counts, int* occPart, int* cntPart, int KSM) {
    __shared__ int so[256], sc[256];
    int t = threadIdx.x;
    int base = blockIdx.x * 1024 + t * 4;
    int o = 0, c = 0;
    for (int r = 0; r < 4; ++r) {
        int k = base + r;
        if (k < KSM) { int cnt = counts[k]; o += (cnt > 0); c += cnt; }
    }
    so[t] = o; sc[t] = c;
    __syncthreads();
    for (int s = 128; s > 0; s >>= 1) {
        if (t < s) { so[t] += so[t + s]; sc[t] += sc[t + s]; }
        __syncthreads();
    }
    if (t == 0) { occPart[blockIdx.x] = so[0]; cntPart[blockIdx.x] = sc[0]; }
}

// ---------- scan pass 3 (pass 2 folded in): full exclusive scans -> krec + cluster tables ----------
// krec[k] = int2{occScan (cluster idx), cntScan (slot base)}: read-only downstream.
__global__ void k_scan3(const int* __restrict__ counts,
                        const int* __restrict__ occPart, const int* __restrict__ cntPart,
                        int2* krec, int* cntC, int* cstartC, int KSM, int NBLK) {
    __shared__ int so[256], sc[256];
    __shared__ int po[128], pc[128];
    __shared__ int poEx, pcEx;
    int t = threadIdx.x;

    // fold of former k_scan2: inclusive scan of block partials in LDS
    if (t < 128) {
        po[t] = (t < NBLK) ? occPart[t] : 0;
        pc[t] = (t < NBLK) ? cntPart[t] : 0;
    }
    __syncthreads();
    for (int s = 1; s < 128; s <<= 1) {
        int ao = 0, ac = 0;
        if (t < 128 && t >= s) { ao = po[t - s]; ac = pc[t - s]; }
        __syncthreads();
        if (t < 128) { po[t] += ao; pc[t] += ac; }
        __syncthreads();
    }
    if (t == 0) {
        int b = blockIdx.x;
        poEx = (b == 0) ? 0 : po[b - 1];
        pcEx = (b == 0) ? 0 : pc[b - 1];
    }
    __syncthreads();

    // original pass 3 body
    int base = blockIdx.x * 1024 + t * 4;
    int o[4], c[4];
    int tO = 0, tC = 0;
    for (int r = 0; r < 4; ++r) {
        int k = base + r;
        int cnt = (k < KSM) ? counts[k] : 0;
        o[r] = (cnt > 0); c[r] = cnt;
        tO += o[r]; tC += c[r];
    }
    so[t] = tO; sc[t] = tC;
    __syncthreads();
    for (int s = 1; s < 256; s <<= 1) {
        int ao = 0, ac = 0;
        if (t >= s) { ao = so[t - s]; ac = sc[t - s]; }
        __syncthreads();
        so[t] += ao; sc[t] += ac;
        __syncthreads();
    }
    int exO = so[t] - tO + poEx;
    int exC = sc[t] - tC + pcEx;
    for (int r = 0; r < 4; ++r) {
        int k = base + r;
        if (k < KSM) {
            krec[k] = make_int2(exO, exC);
            if (c[r] > 0) { cntC[exO] = c[r]; cstartC[exO] = exC; }
            exO += o[r]; exC += c[r];
        }
    }
}

// ---------- slot assignment, ATOMIC-FREE (21 us proven, R5) ----------
// pos = krec[k].y + rank; krec read-only (L2-shared, no ping-pong).
__global__ void k_pos(const int2* __restrict__ vr, const int2* __restrict__ krec,
                      int* __restrict__ plist, float* __restrict__ dout,
                      int N, int B, int M) {
    int i = blockIdx.x * blockDim.x + threadIdx.x;
    if (i >= N) return;
    int2 v = vr[i];                                           // {vkey, rank}, one 8 B
    int2 rec = krec[v.x];                                     // read-only random 8 B
    plist[rec.y + v.y] = i;                                   // 4 B scattered
    dout[(size_t)67 * M + B + i] = (float)rec.x;              // inverse (coalesced)
}

// ---------- fused MLP + segment-max via MFMA: GATHER, FOUR adjacent clusters/iter ----------
// R12 post-mortem: gather k_pool runs at the ~2.4 TB/s random-line rate — it is
// LATENCY-limited (2 independent plist->feat chains/wave), not BW-limited.
// This version holds FOUR independent gather chains in flight and groups
// ADJACENT clusters (c0..c3 = 4gw..4gw+3): their plist windows form one
// contiguous ~100-entry region (L1-hot) and the 4 output rows are 1 KB
// contiguous. All 4 plist loads issue before any feat load; all 8 feat-row
// loads issue before any convert/MFMA -> max memory-level parallelism.
// Max needs no masking (pad rows replicate a real point via clamped idx);
// stats masked by row<cnt (and h1..h3 for duplicated clusters).
__launch_bounds__(64)
__global__ void k_pool(const float* __restrict__ feat, const float* __restrict__ coord,
                       const float* __restrict__ W,
                       const int* __restrict__ cstartC, const int* __restrict__ cntC,
                       const int* __restrict__ plist,
                       float* __restrict__ dout, float* __restrict__ statPart, int M) {
    const int lane = threadIdx.x;
    const int col  = lane & 15;
    const int quad = lane >> 4;
    const int nw = gridDim.x;
    const int gw = blockIdx.x;

    bf16x8 Bf[4];
#pragma unroll
    for (int t = 0; t < 4; ++t) {
#pragma unroll
        for (int j = 0; j < 8; ++j) {
            int k = quad * 8 + j;
            Bf[t][j] = f2bf(W[k * 64 + t * 16 + col]);
        }
    }

    float sumA[4] = {0.f, 0.f, 0.f, 0.f};
    float sqA[4]  = {0.f, 0.f, 0.f, 0.f};

    for (int c0 = 4 * gw; c0 < M; c0 += 4 * nw) {
        int c1 = c0 + 1, c2 = c0 + 2, c3 = c0 + 3;
        bool h1 = (c1 < M), h2 = (c2 < M), h3 = (c3 < M);
        if (!h1) c1 = c0;
        if (!h2) c2 = c0;
        if (!h3) c3 = c0;
        int ps0 = cstartC[c0], n0 = cntC[c0];       // uniform; adjacent -> shared lines
        int ps1 = cstartC[c1], n1 = cntC[c1];
        int ps2 = cstartC[c2], n2 = cntC[c2];
        int ps3 = cstartC[c3], n3 = cntC[c3];
        int nmax = max(max(n0, n1), max(n2, n3));

        float maxA0[4] = {-FLT_MAX, -FLT_MAX, -FLT_MAX, -FLT_MAX};
        float maxA1[4] = {-FLT_MAX, -FLT_MAX, -FLT_MAX, -FLT_MAX};
        float maxA2[4] = {-FLT_MAX, -FLT_MAX, -FLT_MAX, -FLT_MAX};
        float maxA3[4] = {-FLT_MAX, -FLT_MAX, -FLT_MAX, -FLT_MAX};
        float cacc0 = 0.f, cacc1 = 0.f, cacc2 = 0.f, cacc3 = 0.f;

        for (int base = 0; base < nmax; base += 16) {
            int m = base + col;
            int idx0 = min(m, n0 - 1);              // clamp: replicate last real row
            int idx1 = min(m, n1 - 1);
            int idx2 = min(m, n2 - 1);
            int idx3 = min(m, n3 - 1);
            int p0 = plist[ps0 + idx0];             // 4 independent gather chains,
            int p1 = plist[ps1 + idx1];             // issued back-to-back
            int p2 = plist[ps2 + idx2];
            int p3 = plist[ps3 + idx3];
            const float4* r0p = reinterpret_cast<const float4*>(feat + (size_t)p0 * 32 + quad * 8);
            const float4* r1p = reinterpret_cast<const float4*>(feat + (size_t)p1 * 32 + quad * 8);
            const float4* r2p = reinterpret_cast<const float4*>(feat + (size_t)p2 * 32 + quad * 8);
            const float4* r3p = reinterpret_cast<const float4*>(feat + (size_t)p3 * 32 + quad * 8);
            float4 a00 = r0p[0], a01 = r0p[1];
            float4 a10 = r1p[0], a11 = r1p[1];
            float4 a20 = r2p[0], a21 = r2p[1];
            float4 a30 = r3p[0], a31 = r3p[1];
            if (quad > 0) {                         // coord: quads 1..3 load comp quad-1
                float v0 = coord[(size_t)p0 * 3 + (quad - 1)];
                float v1 = coord[(size_t)p1 * 3 + (quad - 1)];
                float v2 = coord[(size_t)p2 * 3 + (quad - 1)];
                float v3 = coord[(size_t)p3 * 3 + (quad - 1)];
                cacc0 += (m < n0) ? v0 : 0.f;
                cacc1 += (m < n1) ? v1 : 0.f;
                cacc2 += (m < n2) ? v2 : 0.f;
                cacc3 += (m < n3) ? v3 : 0.f;
            }
            bf16x8 Af0, Af1, Af2, Af3;
            Af0[0] = f2bf(a00.x); Af0[1] = f2bf(a00.y); Af0[2] = f2bf(a00.z); Af0[3] = f2bf(a00.w);
            Af0[4] = f2bf(a01.x); Af0[5] = f2bf(a01.y); Af0[6] = f2bf(a01.z); Af0[7] = f2bf(a01.w);
            Af1[0] = f2bf(a10.x); Af1[1] = f2bf(a10.y); Af1[2] = f2bf(a10.z); Af1[3] = f2bf(a10.w);
            Af1[4] = f2bf(a11.x); Af1[5] = f2bf(a11.y); Af1[6] = f2bf(a11.z); Af1[7] = f2bf(a11.w);
            Af2[0] = f2bf(a20.x); Af2[1] = f2bf(a20.y); Af2[2] = f2bf(a20.z); Af2[3] = f2bf(a20.w);
            Af2[4] = f2bf(a21.x); Af2[5] = f2bf(a21.y); Af2[6] = f2bf(a21.z); Af2[7] = f2bf(a21.w);
            Af3[0] = f2bf(a30.x); Af3[1] = f2bf(a30.y); Af3[2] = f2bf(a30.z); Af3[3] = f2bf(a30.w);
            Af3[4] = f2bf(a31.x); Af3[5] = f2bf(a31.y); Af3[6] = f2bf(a31.z); Af3[7] = f2bf(a31.w);
            f32x4 Cz = {0.f, 0.f, 0.f, 0.f};
#pragma unroll
            for (int t = 0; t < 4; ++t) {
                f32x4 v0 = __builtin_amdgcn_mfma_f32_16x16x32_bf16(Af0, Bf[t], Cz, 0, 0, 0);
                f32x4 v1 = __builtin_amdgcn_mfma_f32_16x16x32_bf16(Af1, Bf[t], Cz, 0, 0, 0);
                f32x4 v2 = __builtin_amdgcn_mfma_f32_16x16x32_bf16(Af2, Bf[t], Cz, 0, 0, 0);
                f32x4 v3 = __builtin_amdgcn_mfma_f32_16x16x32_bf16(Af3, Bf[t], Cz, 0, 0, 0);
#pragma unroll
                for (int r = 0; r < 4; ++r) {
                    int rowPt = base + quad * 4 + r;
                    maxA0[t] = fmaxf(maxA0[t], v0[r]);          // replication-safe, no mask
                    maxA1[t] = fmaxf(maxA1[t], v1[r]);
                    maxA2[t] = fmaxf(maxA2[t], v2[r]);
                    maxA3[t] = fmaxf(maxA3[t], v3[r]);
                    float m0 = (rowPt < n0) ? v0[r] : 0.f;
                    sumA[t] += m0; sqA[t] = fmaf(m0, m0, sqA[t]);
                    float m1 = (rowPt < n1 && h1) ? v1[r] : 0.f;
                    sumA[t] += m1; sqA[t] = fmaf(m1, m1, sqA[t]);
                    float m2 = (rowPt < n2 && h2) ? v2[r] : 0.f;
                    sumA[t] += m2; sqA[t] = fmaf(m2, m2, sqA[t]);
                    float m3 = (rowPt < n3 && h3) ? v3[r] : 0.f;
                    sumA[t] += m3; sqA[t] = fmaf(m3, m3, sqA[t]);
                }
            }
        }
        // per-channel max writes (duplicate writes for !hk are benign: same data)
        float out0 = 0.f, out1 = 0.f, out2 = 0.f, out3 = 0.f;
#pragma unroll
        for (int t = 0; t < 4; ++t) {
            float v = maxA0[t];
            v = fmaxf(v, __shfl_xor(v, 16, 64));
            v = fmaxf(v, __shfl_xor(v, 32, 64));
            if (quad == t) out0 = v;
            float w = maxA1[t];
            w = fmaxf(w, __shfl_xor(w, 16, 64));
            w = fmaxf(w, __shfl_xor(w, 32, 64));
            if (quad == t) out1 = w;
            float x = maxA2[t];
            x = fmaxf(x, __shfl_xor(x, 16, 64));
            x = fmaxf(x, __shfl_xor(x, 32, 64));
            if (quad == t) out2 = x;
            float y = maxA3[t];
            y = fmaxf(y, __shfl_xor(y, 16, 64));
            y = fmaxf(y, __shfl_xor(y, 32, 64));
            if (quad == t) out3 = y;
        }
        dout[(size_t)3 * M + (size_t)c0 * 64 + lane] = out0;   // 4 adjacent rows:
        dout[(size_t)3 * M + (size_t)c1 * 64 + lane] = out1;   // 1 KB contiguous
        dout[(size_t)3 * M + (size_t)c2 * 64 + lane] = out2;
        dout[(size_t)3 * M + (size_t)c3 * 64 + lane] = out3;

        // coord means: reduce within quad (cols), col-0 of quads 1..3 writes comp quad-1
        cacc0 += __shfl_xor(cacc0, 1, 64); cacc0 += __shfl_xor(cacc0, 2, 64);
        cacc0 += __shfl_xor(cacc0, 4, 64); cacc0 += __shfl_xor(cacc0, 8, 64);
        cacc1 += __shfl_xor(cacc1, 1, 64); cacc1 += __shfl_xor(cacc1, 2, 64);
        cacc1 += __shfl_xor(cacc1, 4, 64); cacc1 += __shfl_xor(cacc1, 8, 64);
        cacc2 += __shfl_xor(cacc2, 1, 64); cacc2 += __shfl_xor(cacc2, 2, 64);
        cacc2 += __shfl_xor(cacc2, 4, 64); cacc2 += __shfl_xor(cacc2, 8, 64);
        cacc3 += __shfl_xor(cacc3, 1, 64); cacc3 += __shfl_xor(cacc3, 2, 64);
        cacc3 += __shfl_xor(cacc3, 4, 64); cacc3 += __shfl_xor(cacc3, 8, 64);
        if (quad > 0 && col == 0) {
            dout[(size_t)c0 * 3 + (quad - 1)] = cacc0 / (float)n0;
            dout[(size_t)c1 * 3 + (quad - 1)] = cacc1 / (float)n1;
            dout[(size_t)c2 * 3 + (quad - 1)] = cacc2 / (float)n2;
            dout[(size_t)c3 * 3 + (quad - 1)] = cacc3 / (float)n3;
        }
    }

    float so = 0.f, qo = 0.f;
#pragma unroll
    for (int t = 0; t < 4; ++t) {
        float s = sumA[t];
        s += __shfl_xor(s, 16, 64);
        s += __shfl_xor(s, 32, 64);
        float q = sqA[t];
        q += __shfl_xor(q, 16, 64);
        q += __shfl_xor(q, 32, 64);
        if (quad == t) { so = s; qo = q; }
    }
    statPart[(size_t)gw * 128 + lane] = so;
    statPart[(size_t)gw * 128 + 64 + lane] = qo;
}

// ---------- reduce stat partials -> BN params (one block per channel) ----------
__global__ void k_statred(const float* __restrict__ statPart,
                          const float* __restrict__ gamma, const float* __restrict__ beta,
                          float* bnA, float* bnB, int NB, int N) {
    __shared__ float s1[256], s2[256];
    int c = blockIdx.x;
    int t = threadIdx.x;
    float a = 0.f, b = 0.f;
    for (int bb = t; bb < NB; bb += 256) {
        a += statPart[(size_t)bb * 128 + c];
        b += statPart[(size_t)bb * 128 + 64 + c];
    }
    s1[t] = a; s2[t] = b;
    __syncthreads();
    for (int s = 128; s > 0; s >>= 1) {
        if (t < s) { s1[t] += s1[t + s]; s2[t] += s2[t + s]; }
        __syncthreads();
    }
    if (t == 0) {
        float invN = 1.0f / (float)N;
        float mean = s1[0] * invN;
        float var = s2[0] * invN - mean * mean;
        float aa = gamma[c] / sqrtf(var + EPSV);
        bnA[c] = aa;
        bnB[c] = beta[c] - mean * aa;
    }
}

// ---------- finalize: BN+ReLU on maxima, offset_out ----------
__global__ void k_final(float* __restrict__ dout, const float* __restrict__ bnA,
                        const float* __restrict__ bnB,
                        const int2* __restrict__ krec, int M, int B) {
    size_t stride = (size_t)gridDim.x * blockDim.x;
    size_t tid0 = (size_t)blockIdx.x * blockDim.x + threadIdx.x;
    size_t totF = (size_t)M * 64;
    for (size_t t = tid0; t < totF; t += stride) {
        int c = (int)(t & 63);
        float v = dout[(size_t)3 * M + t];
        dout[(size_t)3 * M + t] = fmaxf(bnA[c] * v + bnB[c], 0.f);
    }
    if (tid0 < (size_t)B) {
        int val = (tid0 == (size_t)(B - 1)) ? M : krec[(size_t)(tid0 + 1) * DPROD].x;
        dout[(size_t)67 * M + tid0] = (float)val;
    }
}

extern "C" void kernel_launch(void* const* d_in, const int* in_sizes, int n_in,
                              void* d_out, int out_size, void* d_ws, size_t ws_size,
                              hipStream_t stream) {
    const float* coord = (const float*)d_in[0];
    const float* feat  = (const float*)d_in[1];
    const int*   offset = (const int*)d_in[2];
    const float* W     = (const float*)d_in[3];
    const float* gamma = (const float*)d_in[4];
    const float* beta  = (const float*)d_in[5];
    const float* gsP   = (const float*)d_in[6];
    float* dout = (float*)d_out;

    const int N = in_sizes[0] / 3;
    const int B = in_sizes[2];
    const int M = (out_size - B - N) / 67;         // dout layout fixes M
    const int KSM = B * DPROD;                     // conservative keyspace, order-preserving
    const int NBLK = (KSM + 1023) / 1024;          // scan chunks (<=128)
    const int NBPL = 8192;                         // k_pool single-wave blocks

    // workspace layout (int units)
    int* wsI = (int*)d_ws;
    int* startEnc  = wsI + 0;                // B*3
    float* bnA     = (float*)(wsI + 64);     // 64
    float* bnB     = (float*)(wsI + 128);    // 64
    int* occPart   = wsI + 256;              // 128
    int* cntPart   = wsI + 384;              // 128
    int* counts    = wsI + 1024;             // KSM
    int2* krec     = (int2*)(counts + KSM);  // KSM int2 (8 B each; 1024+KSM even -> aligned)
    int* cntC      = (int*)(krec + KSM);     // KSM (>= M)
    int* cstartC   = cntC + KSM;             // KSM (>= M)
    int2* vr       = (int2*)(cstartC + KSM); // N int2 {vkey, rank} (even offset -> aligned)
    int* plist     = (int*)(vr + N);         // N
    float* statPart = (float*)(plist + N);   // NBPL*128 floats

    const int TPB = 256;
    int gChunk = (N + 1023) / 1024;
    int gPoint = (N + TPB - 1) / TPB;

    k_init<<<1, 64, 0, stream>>>(startEnc, B);
    k_start<<<gChunk, TPB, 0, stream>>>(coord, offset, startEnc, counts, KSM, N, B);
    k_count<<<gPoint, TPB, 0, stream>>>(coord, offset, startEnc, gsP, counts, vr, N, B);
    k_scan1<<<NBLK, TPB, 0, stream>>>(counts, occPart, cntPart, KSM);
    k_scan3<<<NBLK, TPB, 0, stream>>>(counts, occPart, cntPart, krec, cntC, cstartC, KSM, NBLK);
    k_pos<<<gPoint, TPB, 0, stream>>>(vr, krec, plist, dout, N, B, M);
    k_pool<<<NBPL, 64, 0, stream>>>(feat, coord, W, cstartC, cntC, plist, dout, statPart, M);
    k_statred<<<64, 256, 0, stream>>>(statPart, gamma, beta, bnA, bnB, NBPL, N);
    k_final<<<1024, TPB, 0, stream>>>(dout, bnA, bnB, krec, M, B);
}